// Round 12
// baseline (475.770 us; speedup 1.0000x reference)
//
#include <hip/hip_runtime.h>

// Problem constants (match reference)
#define NN 50000
#define NE 800000
#define NG 512
#define INF_ 128
#define OUTF 64
#define CAP 64          // max in-degree capacity (Poisson(16): P(deg>64) ~ 1e-20)

// adjacency-build partitioning: 8 dst-ranges (one per XCD) x 250 edge-chunks
#define NPART 8
#define PSIZE 6250      // nodes per part (0.8 MB adj region per part < 4 MB L2)
#define NCHUNK 250
#define CHUNKE 3200     // edges per chunk (250*3200 = 800000)

#define GEMM_BLOCKS ((NN + 63) / 64)          // 782
#define FRONT_BLOCKS 2782

#define XSTRIDE 136     // shorts per staged x row (128 + 8 pad: conflict-free)

__device__ __forceinline__ unsigned short f2bf(float f) {
    unsigned int u = __float_as_uint(f);
    unsigned int r = (u + 0x7fffu + ((u >> 16) & 1u)) >> 16;   // RNE
    return (unsigned short)r;
}
__device__ __forceinline__ float bf2f(unsigned int lo16) {
    return __uint_as_float(lo16 << 16);
}

// ---------------- Fused front: XCD-pinned adjacency + queued GEMM ----------
// R11 falsified the static %8 XCD split (WRITE stayed 42 MB): every XCD's
// private L2 caches its own copy of the whole adj region (8x6.4=51 MB
// aggregate > 32 MB -> thrash -> ~1 line writeback/edge). Fix: discover the
// REAL XCD via s_getreg(HW_REG_XCC_ID) [m09] and drain per-part atomic work
// queues, part == own XCD first (0.8 MB region -> resident, single flush),
// then steal other parts (correctness = slot atomics, never the mapping),
// then drain a gemm-tile queue (Ws staged once per block).
// ctrs[0..7] = per-part chunk counters, ctrs[8] = gemm tile counter; all
// zeroed by the deg memset (adjacent in ws).
__global__ __launch_bounds__(256) void k_front(
    const int* __restrict__ ei, int* __restrict__ deg,
    unsigned short* __restrict__ adj, float* __restrict__ gden,
    float* __restrict__ g_num, int* __restrict__ ctrs,
    const float* __restrict__ x, const float* __restrict__ W,
    const float* __restrict__ att_src, const float* __restrict__ att_dst,
    unsigned short* __restrict__ hb, float* __restrict__ a_s,
    float* __restrict__ a_d)
{
    __shared__ float Ws[INF_ * OUTF];            // 32 KB
    __shared__ unsigned short Xs[64 * XSTRIDE];  // 17 KB
    __shared__ int s_work;

    {   // zero gden/g_num (any grid >= 131 blocks covers it)
        int idx = blockIdx.x * 256 + threadIdx.x;
        if (idx < NG) gden[idx] = 0.f;
        else if (idx < NG + NG * OUTF) g_num[idx - NG] = 0.f;
    }

    unsigned int xcd;
    asm volatile("s_getreg_b32 %0, hwreg(HW_REG_XCC_ID)" : "=s"(xcd));
    xcd &= 7;

    // ---- adjacency: drain own part's queue, then steal others ----
    for (int off = 0; off < NPART; off++) {
        const int p  = (xcd + off) & (NPART - 1);
        const int lo = p * PSIZE;
        for (;;) {
            __syncthreads();
            if (threadIdx.x == 0) s_work = atomicAdd(&ctrs[p], 1);
            __syncthreads();
            const int c = s_work;
            if (c >= NCHUNK) break;
            const int e0 = c * CHUNKE;
            const int e1 = (e0 + CHUNKE < NE) ? e0 + CHUNKE : NE;
            for (int e = e0 + threadIdx.x; e < e1; e += 256) {
                int d = ei[NE + e];
                unsigned int rel = (unsigned int)(d - lo);
                if (rel < PSIZE) {
                    int s = ei[e];
                    int pos = atomicAdd(&deg[d], 1);
                    if (pos < CAP) adj[(size_t)d * CAP + pos] = (unsigned short)s;
                }
            }
        }
    }

    // ---- GEMM: stage Ws once, then drain the tile queue ----
    for (int i = threadIdx.x; i < INF_ * OUTF / 4; i += 256)
        ((float4*)Ws)[i] = ((const float4*)W)[i];

    const int colg = threadIdx.x & 15;
    const int rowg = threadIdx.x >> 4;
    float asv[4], adv[4];
    #pragma unroll
    for (int c = 0; c < 4; c++) {
        asv[c] = att_src[colg * 4 + c];
        adv[c] = att_dst[colg * 4 + c];
    }

    for (;;) {
        __syncthreads();                       // protects s_work + Xs WAR
        if (threadIdx.x == 0) s_work = atomicAdd(&ctrs[NPART], 1);
        __syncthreads();
        const int bid = s_work;
        if (bid >= GEMM_BLOCKS) break;
        const int n0 = bid * 64;

        // stage x tile: 64 rows x 128 cols, coalesced float4 -> bf16 LDS
        #pragma unroll
        for (int it = 0; it < 8; it++) {
            int idx = it * 256 + threadIdx.x;  // float4 granule id
            int row = idx >> 5;                // 32 float4 per row
            int c4  = idx & 31;
            int n = n0 + row;
            if (n > NN - 1) n = NN - 1;        // clamp tail (stores guarded)
            float4 v = ((const float4*)(x + (size_t)n * INF_))[c4];
            ushort4 b;
            b.x = f2bf(v.x); b.y = f2bf(v.y); b.z = f2bf(v.z); b.w = f2bf(v.w);
            *(ushort4*)&Xs[row * XSTRIDE + c4 * 4] = b;
        }
        __syncthreads();

        const unsigned short* xr[4];
        #pragma unroll
        for (int rr = 0; rr < 4; rr++)
            xr[rr] = &Xs[(rowg * 4 + rr) * XSTRIDE];

        float acc[4][4];
        #pragma unroll
        for (int rr = 0; rr < 4; rr++)
            #pragma unroll
            for (int c = 0; c < 4; c++) acc[rr][c] = 0.f;

        for (int k8 = 0; k8 < INF_ / 8; k8++) {
            uint4 xv[4];                       // 8 bf16 per row
            #pragma unroll
            for (int rr = 0; rr < 4; rr++)
                xv[rr] = *(const uint4*)(xr[rr] + k8 * 8);
            #pragma unroll
            for (int kk = 0; kk < 8; kk++) {
                float4 wv = ((const float4*)&Ws[(k8 * 8 + kk) * OUTF])[colg];
                #pragma unroll
                for (int rr = 0; rr < 4; rr++) {
                    unsigned int pair = ((const unsigned int*)&xv[rr])[kk >> 1];
                    float xs_ = bf2f((kk & 1) ? (pair >> 16) : (pair & 0xffffu));
                    acc[rr][0] = fmaf(xs_, wv.x, acc[rr][0]);
                    acc[rr][1] = fmaf(xs_, wv.y, acc[rr][1]);
                    acc[rr][2] = fmaf(xs_, wv.z, acc[rr][2]);
                    acc[rr][3] = fmaf(xs_, wv.w, acc[rr][3]);
                }
            }
        }

        #pragma unroll
        for (int rr = 0; rr < 4; rr++) {
            const int n = n0 + rowg * 4 + rr;
            const bool valid = (n < NN);
            if (valid) {
                ushort4 o;
                o.x = f2bf(acc[rr][0]); o.y = f2bf(acc[rr][1]);
                o.z = f2bf(acc[rr][2]); o.w = f2bf(acc[rr][3]);
                ((ushort4*)(hb + (size_t)n * OUTF))[colg] = o;
            }
            float vs = acc[rr][0]*asv[0] + acc[rr][1]*asv[1] + acc[rr][2]*asv[2] + acc[rr][3]*asv[3];
            float vd = acc[rr][0]*adv[0] + acc[rr][1]*adv[1] + acc[rr][2]*adv[2] + acc[rr][3]*adv[3];
            vs += __shfl_xor(vs, 1, 64);       // lane pair (colg, colg^1) = one head
            vd += __shfl_xor(vd, 1, 64);
            if (valid && !(colg & 1)) {
                a_s[n * 8 + (colg >> 1)] = vs;
                a_d[n * 8 + (colg >> 1)] = vd;
            }
        }
    }
}

// ---------------- GAT aggregation: wave = 8 edge-slots x 8 col-octets ------
__global__ __launch_bounds__(256) void k_aggr(
    const unsigned short* __restrict__ hb, const float* __restrict__ a_s,
    const float* __restrict__ a_d, const int* __restrict__ deg,
    const unsigned short* __restrict__ adj, const float* __restrict__ bias,
    const float* __restrict__ w_rel, const float* __restrict__ w_root,
    float* __restrict__ out, float* __restrict__ t_rel, float* __restrict__ t_root)
{
    const int wid  = threadIdx.x >> 6;
    const int lane = threadIdx.x & 63;
    const int g    = lane >> 3;     // edge slot 0..7
    const int c8   = lane & 7;      // head / col-octet 0..7
    const int n    = blockIdx.x * 4 + wid;
    if (n >= NN) return;

    const float ad_n = a_d[n * 8 + c8];

    float acc[8];
    #pragma unroll
    for (int k = 0; k < 8; k++) acc[k] = 0.f;
    float den = 0.f;

    // self-loop handled by edge slot 0
    if (g == 0) {
        float e0 = a_s[n * 8 + c8] + ad_n;
        e0 = e0 > 0.f ? e0 : 0.2f * e0;
        float ex0 = __expf(e0);
        uint4 hv = *(const uint4*)(hb + (size_t)n * OUTF + c8 * 8);
        acc[0] = ex0 * bf2f(hv.x & 0xffffu); acc[1] = ex0 * bf2f(hv.x >> 16);
        acc[2] = ex0 * bf2f(hv.y & 0xffffu); acc[3] = ex0 * bf2f(hv.y >> 16);
        acc[4] = ex0 * bf2f(hv.z & 0xffffu); acc[5] = ex0 * bf2f(hv.z >> 16);
        acc[6] = ex0 * bf2f(hv.w & 0xffffu); acc[7] = ex0 * bf2f(hv.w >> 16);
        den = ex0;
    }

    const int cnt = min(deg[n], CAP);
    const unsigned short* lst = adj + (size_t)n * CAP;
    for (int i = g; i < cnt; i += 8) {
        int s = lst[i];                                   // uniform per group
        float as = a_s[s * 8 + c8];
        uint4 hv = *(const uint4*)(hb + (size_t)s * OUTF + c8 * 8);
        float e = as + ad_n;
        e = e > 0.f ? e : 0.2f * e;
        float ex = __expf(e);
        acc[0] = fmaf(ex, bf2f(hv.x & 0xffffu), acc[0]);
        acc[1] = fmaf(ex, bf2f(hv.x >> 16),     acc[1]);
        acc[2] = fmaf(ex, bf2f(hv.y & 0xffffu), acc[2]);
        acc[3] = fmaf(ex, bf2f(hv.y >> 16),     acc[3]);
        acc[4] = fmaf(ex, bf2f(hv.z & 0xffffu), acc[4]);
        acc[5] = fmaf(ex, bf2f(hv.z >> 16),     acc[5]);
        acc[6] = fmaf(ex, bf2f(hv.w & 0xffffu), acc[6]);
        acc[7] = fmaf(ex, bf2f(hv.w >> 16),     acc[7]);
        den += ex;
    }

    // butterfly reduce across edge slots (g bits = lane bits 3..5)
    #pragma unroll
    for (int m = 8; m < 64; m <<= 1) {
        den += __shfl_xor(den, m, 64);
        #pragma unroll
        for (int k = 0; k < 8; k++) acc[k] += __shfl_xor(acc[k], m, 64);
    }

    const float inv = 1.f / (den + 1e-16f);
    float o[8];
    #pragma unroll
    for (int k = 0; k < 8; k++) o[k] = acc[k] * inv + bias[c8 * 8 + k];

    if (g == 0) {
        float4 o0 = make_float4(o[0], o[1], o[2], o[3]);
        float4 o1 = make_float4(o[4], o[5], o[6], o[7]);
        float4* op = (float4*)(out + (size_t)n * OUTF + c8 * 8);
        op[0] = o0; op[1] = o1;
    }

    // pooling-score projections: vr = sum_j o_j*w_rel_j (cols dup across g)
    float vr = 0.f, vt = 0.f;
    #pragma unroll
    for (int k = 0; k < 8; k++) {
        vr = fmaf(o[k], w_rel[c8 * 8 + k], vr);
        vt = fmaf(o[k], w_root[c8 * 8 + k], vt);
    }
    #pragma unroll
    for (int m = 1; m < 8; m <<= 1) {
        vr += __shfl_xor(vr, m, 64);
        vt += __shfl_xor(vt, m, 64);
    }
    if (lane == 0) { t_rel[n] = vr; t_root[n] = vt; }
}

// ---------------- fused pooling: score gather + softmax-numerator pool -----
__global__ __launch_bounds__(256) void k_score_pool(
    const int* __restrict__ deg, const unsigned short* __restrict__ adj,
    const float* __restrict__ t_rel, const float* __restrict__ t_root,
    const float* __restrict__ pool_b, const int* __restrict__ batch,
    const float* __restrict__ out,
    float* __restrict__ gden, float* __restrict__ g_num)
{
    __shared__ float ex_s[32];
    __shared__ int   b_s[32];

    const int wid  = threadIdx.x >> 6;
    const int lane = threadIdx.x & 63;
    const int sub  = lane >> 3;     // node within wave (0..7)
    const int g    = lane & 7;      // slot
    const int base_n = blockIdx.x * 32;
    const int n    = base_n + wid * 8 + sub;

    const int cnt = (n < NN) ? min(deg[n], CAP) : 0;
    const unsigned short* lst = adj + (size_t)n * CAP;
    float acc = 0.f;
    for (int i = g; i < cnt; i += 8) acc += t_rel[lst[i]];
    #pragma unroll
    for (int m = 1; m < 8; m <<= 1) acc += __shfl_xor(acc, m, 64);

    if (g == 0) {
        const int slot = wid * 8 + sub;
        if (n < NN) {
            float ex = __expf(acc + t_root[n] + pool_b[0]);
            ex_s[slot] = ex;
            b_s[slot]  = batch[n];
        } else {
            ex_s[slot] = 0.f;
            b_s[slot]  = -1;
        }
    }
    __syncthreads();

    if (threadIdx.x == 0) {           // gden run-length flush (batch sorted)
        float racc = 0.f;
        int bcur = -1;
        for (int i = 0; i < 32; i++) {
            int b = b_s[i];
            if (b != bcur) {
                if (bcur >= 0) atomicAdd(&gden[bcur], racc);
                bcur = b; racc = 0.f;
            }
            racc += ex_s[i];
        }
        if (bcur >= 0) atomicAdd(&gden[bcur], racc);
    }

    // phase 2: wave wid accumulates its 8 nodes; lane = feature j
    const int j = lane;
    float facc = 0.f;
    int bcur = -1;
    for (int i = 0; i < 8; i++) {
        const int slot = wid * 8 + i;
        const int n2 = base_n + slot;
        if (n2 >= NN) break;
        int b = b_s[slot];                         // wave-uniform
        if (b != bcur) {
            if (bcur >= 0) atomicAdd(&g_num[bcur * OUTF + j], facc);
            bcur = b; facc = 0.f;
        }
        facc = fmaf(out[(size_t)n2 * OUTF + j], ex_s[slot], facc);
    }
    if (bcur >= 0) atomicAdd(&g_num[bcur * OUTF + j], facc);
}

// ---------------- g[b,j] = g_num[b,j] / (gden[b] + eps) --------------------
__global__ __launch_bounds__(256) void k_gfinal(
    const float* __restrict__ g_num, const float* __restrict__ gden,
    float* __restrict__ g)
{
    int i = blockIdx.x * 256 + threadIdx.x;
    if (i < NG * OUTF) g[i] = g_num[i] / (gden[i >> 6] + 1e-16f);
}

extern "C" void kernel_launch(void* const* d_in, const int* in_sizes, int n_in,
                              void* d_out, int out_size, void* d_ws, size_t ws_size,
                              hipStream_t stream)
{
    const float* x        = (const float*)d_in[0];
    const int*   ei       = (const int*)  d_in[1];
    const int*   batch    = (const int*)  d_in[2];
    const float* W        = (const float*)d_in[3];
    const float* att_src  = (const float*)d_in[4];
    const float* att_dst  = (const float*)d_in[5];
    const float* bias     = (const float*)d_in[6];
    const float* w_rel    = (const float*)d_in[7];
    const float* pool_b   = (const float*)d_in[8];
    const float* w_root   = (const float*)d_in[9];

    float* out_nodes = (float*)d_out;                       // [NN,64]
    float* g_out     = (float*)d_out + (size_t)NN * OUTF;   // [NG,64]

    // workspace layout (bytes)
    char* base = (char*)d_ws;
    unsigned short* hb = (unsigned short*)(base);           //  6,400,000 B
    float* a_s       = (float*)(base +  6400000);           //  1,600,000 B
    float* a_d       = (float*)(base +  8000000);           //  1,600,000 B
    float* t_rel     = (float*)(base +  9600000);           //    200,000 B
    float* t_root    = (float*)(base +  9800000);           //    200,000 B
    float* gden      = (float*)(base + 10000000);           //      2,048 B
    float* g_num     = (float*)(base + 10002048);           //    131,072 B
    int*   deg       = (int*)  (base + 10133120);           //    200,000 B
    int*   ctrs     = (int*)   (base + 10333120);           //         64 B (9 used)
    unsigned short* adjl = (unsigned short*)(base + 10333184); // 6,400,000 B
    // total: 16,733,184 B

    // zero deg + work-queue counters in one memset
    hipMemsetAsync(deg, 0, (size_t)NN * 4 + 64, stream);

    k_front<<<FRONT_BLOCKS, 256, 0, stream>>>(
        ei, deg, adjl, gden, g_num, ctrs,
        x, W, att_src, att_dst, hb, a_s, a_d);
    k_aggr<<<(NN + 3) / 4, 256, 0, stream>>>(hb, a_s, a_d, deg, adjl, bias,
                                             w_rel, w_root, out_nodes, t_rel, t_root);
    k_score_pool<<<(NN + 31) / 32, 256, 0, stream>>>(deg, adjl, t_rel, t_root,
                                                     pool_b, batch, out_nodes,
                                                     gden, g_num);
    k_gfinal<<<(NG * OUTF + 255) / 256, 256, 0, stream>>>(g_num, gden, g_out);
}

// Round 13
// 193.521 us; speedup vs baseline: 2.4585x; 2.4585x over previous
//
#include <hip/hip_runtime.h>

// Problem constants (match reference)
#define NN 50000
#define NE 800000
#define NG 512
#define INF_ 128
#define OUTF 64
#define CAP 48          // max in-degree capacity (Poisson(16): max deg over 50k
                        // nodes ~ 36-40; P(any > 48) ~ 5e-7)

// adjacency-build partitioning: 2 dst-ranges x 250 edge-chunks
#define NPART 2
#define PSIZE 25000     // nodes per part
#define NCHUNK 250
#define CHUNKE 3200     // edges per chunk (250*3200 = 800000)

#define GEMM_BLOCKS ((NN + 63) / 64)          // 782
#define FRONT_BLOCKS (NCHUNK * 8)             // 2000: 2 adj + 6 gemm lanes per octet

#define XSTRIDE 136     // shorts per staged x row (128 + 8 pad: conflict-free)

__device__ __forceinline__ unsigned short f2bf(float f) {
    unsigned int u = __float_as_uint(f);
    unsigned int r = (u + 0x7fffu + ((u >> 16) & 1u)) >> 16;   // RNE
    return (unsigned short)r;
}
__device__ __forceinline__ float bf2f(unsigned int lo16) {
    return __uint_as_float(lo16 << 16);
}

// ---------------- Fused front: adjacency build + GEMM (R11 structure) ------
// Octet split: r = blockIdx&7; r<2 -> adjacency part r (halved rescan work
// vs NPART=4: each dst read 2x total); r>=2 -> gemm tile (6/8 of machine).
// R12 post-mortem: work queues serialize (barriers+atomics, 476 us) and
// WRITE~40MB is invariant under ALL placement schemes (R7-R12) — accepted
// as a ~7 us HBM cost. Scan work, not writes, is the lever.
__global__ __launch_bounds__(256) void k_front(
    const int* __restrict__ ei, int* __restrict__ deg,
    unsigned short* __restrict__ adj, float* __restrict__ gden,
    float* __restrict__ g_num,
    const float* __restrict__ x, const float* __restrict__ W,
    const float* __restrict__ att_src, const float* __restrict__ att_dst,
    unsigned short* __restrict__ hb, float* __restrict__ a_s,
    float* __restrict__ a_d)
{
    __shared__ float Ws[INF_ * OUTF];            // 32 KB (gemm part only)
    __shared__ unsigned short Xs[64 * XSTRIDE];  // 17 KB (gemm part only)

    {   // zero gden/g_num (needs first 131 blocks; grid = 2000)
        int idx = blockIdx.x * 256 + threadIdx.x;
        if (idx < NG) gden[idx] = 0.f;
        else if (idx < NG + NG * OUTF) g_num[idx - NG] = 0.f;
    }

    const int r   = blockIdx.x & 7;
    const int oct = blockIdx.x >> 3;

    if (r < NPART) {
        // ---------------- adjacency part ----------------
        const int lo = r * PSIZE;                // part r's dst range
        const int e0 = oct * CHUNKE;
        const int e1 = (e0 + CHUNKE < NE) ? e0 + CHUNKE : NE;
        for (int e = e0 + threadIdx.x; e < e1; e += 256) {
            int d = ei[NE + e];
            unsigned int rel = (unsigned int)(d - lo);
            if (rel < PSIZE) {
                int s = ei[e];
                int p = atomicAdd(&deg[d], 1);
                if (p < CAP) adj[(size_t)d * CAP + p] = (unsigned short)s;
            }
        }
        return;
    }

    // ---------------- GEMM part ----------------
    const int bid = oct * 6 + (r - 2);           // 0..1499, need <782
    if (bid >= GEMM_BLOCKS) return;
    const int n0 = bid * 64;

    for (int i = threadIdx.x; i < INF_ * OUTF / 4; i += 256)
        ((float4*)Ws)[i] = ((const float4*)W)[i];

    // stage x tile: 64 rows x 128 cols, coalesced float4 loads -> bf16 LDS
    #pragma unroll
    for (int it = 0; it < 8; it++) {
        int idx = it * 256 + threadIdx.x;      // float4 granule id
        int row = idx >> 5;                    // 32 float4 per row
        int c4  = idx & 31;
        int n = n0 + row;
        if (n > NN - 1) n = NN - 1;            // clamp tail (stores guarded)
        float4 v = ((const float4*)(x + (size_t)n * INF_))[c4];
        ushort4 b;
        b.x = f2bf(v.x); b.y = f2bf(v.y); b.z = f2bf(v.z); b.w = f2bf(v.w);
        *(ushort4*)&Xs[row * XSTRIDE + c4 * 4] = b;
    }
    __syncthreads();

    const int colg = threadIdx.x & 15;
    const int rowg = threadIdx.x >> 4;

    const unsigned short* xr[4];
    #pragma unroll
    for (int rr = 0; rr < 4; rr++)
        xr[rr] = &Xs[(rowg * 4 + rr) * XSTRIDE];

    float acc[4][4];
    #pragma unroll
    for (int rr = 0; rr < 4; rr++)
        #pragma unroll
        for (int c = 0; c < 4; c++) acc[rr][c] = 0.f;

    for (int k8 = 0; k8 < INF_ / 8; k8++) {
        uint4 xv[4];                           // 8 bf16 per row
        #pragma unroll
        for (int rr = 0; rr < 4; rr++)
            xv[rr] = *(const uint4*)(xr[rr] + k8 * 8);
        #pragma unroll
        for (int kk = 0; kk < 8; kk++) {
            float4 wv = ((const float4*)&Ws[(k8 * 8 + kk) * OUTF])[colg];
            #pragma unroll
            for (int rr = 0; rr < 4; rr++) {
                unsigned int pair = ((const unsigned int*)&xv[rr])[kk >> 1];
                float xs_ = bf2f((kk & 1) ? (pair >> 16) : (pair & 0xffffu));
                acc[rr][0] = fmaf(xs_, wv.x, acc[rr][0]);
                acc[rr][1] = fmaf(xs_, wv.y, acc[rr][1]);
                acc[rr][2] = fmaf(xs_, wv.z, acc[rr][2]);
                acc[rr][3] = fmaf(xs_, wv.w, acc[rr][3]);
            }
        }
    }

    float asv[4], adv[4];
    #pragma unroll
    for (int c = 0; c < 4; c++) {
        asv[c] = att_src[colg * 4 + c];
        adv[c] = att_dst[colg * 4 + c];
    }

    #pragma unroll
    for (int rr = 0; rr < 4; rr++) {
        const int n = n0 + rowg * 4 + rr;
        const bool valid = (n < NN);
        if (valid) {
            ushort4 o;
            o.x = f2bf(acc[rr][0]); o.y = f2bf(acc[rr][1]);
            o.z = f2bf(acc[rr][2]); o.w = f2bf(acc[rr][3]);
            ((ushort4*)(hb + (size_t)n * OUTF))[colg] = o;
        }
        float vs = acc[rr][0]*asv[0] + acc[rr][1]*asv[1] + acc[rr][2]*asv[2] + acc[rr][3]*asv[3];
        float vd = acc[rr][0]*adv[0] + acc[rr][1]*adv[1] + acc[rr][2]*adv[2] + acc[rr][3]*adv[3];
        vs += __shfl_xor(vs, 1, 64);           // lane pair (colg, colg^1) = one head
        vd += __shfl_xor(vd, 1, 64);
        if (valid && !(colg & 1)) {
            a_s[n * 8 + (colg >> 1)] = vs;
            a_d[n * 8 + (colg >> 1)] = vd;
        }
    }
}

// ---------------- GAT aggregation: wave = 8 edge-slots x 8 col-octets ------
__global__ __launch_bounds__(256) void k_aggr(
    const unsigned short* __restrict__ hb, const float* __restrict__ a_s,
    const float* __restrict__ a_d, const int* __restrict__ deg,
    const unsigned short* __restrict__ adj, const float* __restrict__ bias,
    const float* __restrict__ w_rel, const float* __restrict__ w_root,
    float* __restrict__ out, float* __restrict__ t_rel, float* __restrict__ t_root)
{
    const int wid  = threadIdx.x >> 6;
    const int lane = threadIdx.x & 63;
    const int g    = lane >> 3;     // edge slot 0..7
    const int c8   = lane & 7;      // head / col-octet 0..7
    const int n    = blockIdx.x * 4 + wid;
    if (n >= NN) return;

    const float ad_n = a_d[n * 8 + c8];

    float acc[8];
    #pragma unroll
    for (int k = 0; k < 8; k++) acc[k] = 0.f;
    float den = 0.f;

    // self-loop handled by edge slot 0
    if (g == 0) {
        float e0 = a_s[n * 8 + c8] + ad_n;
        e0 = e0 > 0.f ? e0 : 0.2f * e0;
        float ex0 = __expf(e0);
        uint4 hv = *(const uint4*)(hb + (size_t)n * OUTF + c8 * 8);
        acc[0] = ex0 * bf2f(hv.x & 0xffffu); acc[1] = ex0 * bf2f(hv.x >> 16);
        acc[2] = ex0 * bf2f(hv.y & 0xffffu); acc[3] = ex0 * bf2f(hv.y >> 16);
        acc[4] = ex0 * bf2f(hv.z & 0xffffu); acc[5] = ex0 * bf2f(hv.z >> 16);
        acc[6] = ex0 * bf2f(hv.w & 0xffffu); acc[7] = ex0 * bf2f(hv.w >> 16);
        den = ex0;
    }

    const int cnt = min(deg[n], CAP);
    const unsigned short* lst = adj + (size_t)n * CAP;
    for (int i = g; i < cnt; i += 8) {
        int s = lst[i];                                   // uniform per group
        float as = a_s[s * 8 + c8];
        uint4 hv = *(const uint4*)(hb + (size_t)s * OUTF + c8 * 8);
        float e = as + ad_n;
        e = e > 0.f ? e : 0.2f * e;
        float ex = __expf(e);
        acc[0] = fmaf(ex, bf2f(hv.x & 0xffffu), acc[0]);
        acc[1] = fmaf(ex, bf2f(hv.x >> 16),     acc[1]);
        acc[2] = fmaf(ex, bf2f(hv.y & 0xffffu), acc[2]);
        acc[3] = fmaf(ex, bf2f(hv.y >> 16),     acc[3]);
        acc[4] = fmaf(ex, bf2f(hv.z & 0xffffu), acc[4]);
        acc[5] = fmaf(ex, bf2f(hv.z >> 16),     acc[5]);
        acc[6] = fmaf(ex, bf2f(hv.w & 0xffffu), acc[6]);
        acc[7] = fmaf(ex, bf2f(hv.w >> 16),     acc[7]);
        den += ex;
    }

    // butterfly reduce across edge slots (g bits = lane bits 3..5)
    #pragma unroll
    for (int m = 8; m < 64; m <<= 1) {
        den += __shfl_xor(den, m, 64);
        #pragma unroll
        for (int k = 0; k < 8; k++) acc[k] += __shfl_xor(acc[k], m, 64);
    }

    const float inv = 1.f / (den + 1e-16f);
    float o[8];
    #pragma unroll
    for (int k = 0; k < 8; k++) o[k] = acc[k] * inv + bias[c8 * 8 + k];

    if (g == 0) {
        float4 o0 = make_float4(o[0], o[1], o[2], o[3]);
        float4 o1 = make_float4(o[4], o[5], o[6], o[7]);
        float4* op = (float4*)(out + (size_t)n * OUTF + c8 * 8);
        op[0] = o0; op[1] = o1;
    }

    // pooling-score projections: vr = sum_j o_j*w_rel_j (cols dup across g)
    float vr = 0.f, vt = 0.f;
    #pragma unroll
    for (int k = 0; k < 8; k++) {
        vr = fmaf(o[k], w_rel[c8 * 8 + k], vr);
        vt = fmaf(o[k], w_root[c8 * 8 + k], vt);
    }
    #pragma unroll
    for (int m = 1; m < 8; m <<= 1) {
        vr += __shfl_xor(vr, m, 64);
        vt += __shfl_xor(vt, m, 64);
    }
    if (lane == 0) { t_rel[n] = vr; t_root[n] = vt; }
}

// ---------------- fused pooling: score gather + softmax-numerator pool -----
__global__ __launch_bounds__(256) void k_score_pool(
    const int* __restrict__ deg, const unsigned short* __restrict__ adj,
    const float* __restrict__ t_rel, const float* __restrict__ t_root,
    const float* __restrict__ pool_b, const int* __restrict__ batch,
    const float* __restrict__ out,
    float* __restrict__ gden, float* __restrict__ g_num)
{
    __shared__ float ex_s[32];
    __shared__ int   b_s[32];

    const int wid  = threadIdx.x >> 6;
    const int lane = threadIdx.x & 63;
    const int sub  = lane >> 3;     // node within wave (0..7)
    const int g    = lane & 7;      // slot
    const int base_n = blockIdx.x * 32;
    const int n    = base_n + wid * 8 + sub;

    const int cnt = (n < NN) ? min(deg[n], CAP) : 0;
    const unsigned short* lst = adj + (size_t)n * CAP;
    float acc = 0.f;
    for (int i = g; i < cnt; i += 8) acc += t_rel[lst[i]];
    #pragma unroll
    for (int m = 1; m < 8; m <<= 1) acc += __shfl_xor(acc, m, 64);

    if (g == 0) {
        const int slot = wid * 8 + sub;
        if (n < NN) {
            float ex = __expf(acc + t_root[n] + pool_b[0]);
            ex_s[slot] = ex;
            b_s[slot]  = batch[n];
        } else {
            ex_s[slot] = 0.f;
            b_s[slot]  = -1;
        }
    }
    __syncthreads();

    if (threadIdx.x == 0) {           // gden run-length flush (batch sorted)
        float racc = 0.f;
        int bcur = -1;
        for (int i = 0; i < 32; i++) {
            int b = b_s[i];
            if (b != bcur) {
                if (bcur >= 0) atomicAdd(&gden[bcur], racc);
                bcur = b; racc = 0.f;
            }
            racc += ex_s[i];
        }
        if (bcur >= 0) atomicAdd(&gden[bcur], racc);
    }

    // phase 2: wave wid accumulates its 8 nodes; lane = feature j
    const int j = lane;
    float facc = 0.f;
    int bcur = -1;
    for (int i = 0; i < 8; i++) {
        const int slot = wid * 8 + i;
        const int n2 = base_n + slot;
        if (n2 >= NN) break;
        int b = b_s[slot];                         // wave-uniform
        if (b != bcur) {
            if (bcur >= 0) atomicAdd(&g_num[bcur * OUTF + j], facc);
            bcur = b; facc = 0.f;
        }
        facc = fmaf(out[(size_t)n2 * OUTF + j], ex_s[slot], facc);
    }
    if (bcur >= 0) atomicAdd(&g_num[bcur * OUTF + j], facc);
}

// ---------------- g[b,j] = g_num[b,j] / (gden[b] + eps) --------------------
__global__ __launch_bounds__(256) void k_gfinal(
    const float* __restrict__ g_num, const float* __restrict__ gden,
    float* __restrict__ g)
{
    int i = blockIdx.x * 256 + threadIdx.x;
    if (i < NG * OUTF) g[i] = g_num[i] / (gden[i >> 6] + 1e-16f);
}

extern "C" void kernel_launch(void* const* d_in, const int* in_sizes, int n_in,
                              void* d_out, int out_size, void* d_ws, size_t ws_size,
                              hipStream_t stream)
{
    const float* x        = (const float*)d_in[0];
    const int*   ei       = (const int*)  d_in[1];
    const int*   batch    = (const int*)  d_in[2];
    const float* W        = (const float*)d_in[3];
    const float* att_src  = (const float*)d_in[4];
    const float* att_dst  = (const float*)d_in[5];
    const float* bias     = (const float*)d_in[6];
    const float* w_rel    = (const float*)d_in[7];
    const float* pool_b   = (const float*)d_in[8];
    const float* w_root   = (const float*)d_in[9];

    float* out_nodes = (float*)d_out;                       // [NN,64]
    float* g_out     = (float*)d_out + (size_t)NN * OUTF;   // [NG,64]

    // workspace layout (bytes)
    char* base = (char*)d_ws;
    unsigned short* hb = (unsigned short*)(base);           //  6,400,000 B
    float* a_s       = (float*)(base +  6400000);           //  1,600,000 B
    float* a_d       = (float*)(base +  8000000);           //  1,600,000 B
    float* t_rel     = (float*)(base +  9600000);           //    200,000 B
    float* t_root    = (float*)(base +  9800000);           //    200,000 B
    float* gden      = (float*)(base + 10000000);           //      2,048 B
    float* g_num     = (float*)(base + 10002048);           //    131,072 B
    int*   deg       = (int*)  (base + 10133120);           //    200,000 B
    unsigned short* adjl = (unsigned short*)(base + 10333120); // 4,800,000 B
    // total: 15,133,120 B

    hipMemsetAsync(deg, 0, (size_t)NN * 4, stream);   // adj part needs zeroed deg

    k_front<<<FRONT_BLOCKS, 256, 0, stream>>>(
        ei, deg, adjl, gden, g_num,
        x, W, att_src, att_dst, hb, a_s, a_d);
    k_aggr<<<(NN + 3) / 4, 256, 0, stream>>>(hb, a_s, a_d, deg, adjl, bias,
                                             w_rel, w_root, out_nodes, t_rel, t_root);
    k_score_pool<<<(NN + 31) / 32, 256, 0, stream>>>(deg, adjl, t_rel, t_root,
                                                     pool_b, batch, out_nodes,
                                                     gden, g_num);
    k_gfinal<<<(NG * OUTF + 255) / 256, 256, 0, stream>>>(g_num, gden, g_out);
}

// Round 14
// 174.077 us; speedup vs baseline: 2.7331x; 1.1117x over previous
//
#include <hip/hip_runtime.h>

// Problem constants (match reference)
#define NN 50000
#define NE 800000
#define NG 512
#define INF_ 128
#define OUTF 64
#define CAP 64          // max in-degree capacity (Poisson(16): P(deg>64) ~ 1e-20)

// adjacency-build partitioning: 4 dst-ranges x 250 edge-chunks (R11 config)
#define NPART 4
#define PSIZE 12500     // nodes per part
#define NCHUNK 250
#define CHUNKE 3200     // edges per chunk (250*3200 = 800000)

#define GEMM_BLOCKS ((NN + 63) / 64)          // 782
#define FRONT_BLOCKS (NCHUNK * 8)             // 2000: 4 adj + 4 gemm lanes per octet

#define XSTRIDE 136     // shorts per staged x row (128 + 8 pad: conflict-free)

__device__ __forceinline__ unsigned short f2bf(float f) {
    unsigned int u = __float_as_uint(f);
    unsigned int r = (u + 0x7fffu + ((u >> 16) & 1u)) >> 16;   // RNE
    return (unsigned short)r;
}
__device__ __forceinline__ float bf2f(unsigned int lo16) {
    return __uint_as_float(lo16 << 16);
}

// ---------------- Fused front: adjacency build + GEMM (R11 structure) ------
// Octet split: r = blockIdx&7; r<4 -> adjacency part r; r>=4 -> gemm tile.
// R12/R13 lessons: WRITE~40MB is per-edge atomic-RMW traffic, invariant
// under every placement scheme (accepted); NPART=2 lengthens the adj tail.
// R14 change: W staged in LDS as bf16 (32->16 KB; total LDS 50->33 KB) ->
// 4 blocks/CU instead of 3. Expansion cost ~7 VALU per 16 FMAs.
__global__ __launch_bounds__(256) void k_front(
    const int* __restrict__ ei, int* __restrict__ deg,
    unsigned short* __restrict__ adj, float* __restrict__ gden,
    float* __restrict__ g_num,
    const float* __restrict__ x, const float* __restrict__ W,
    const float* __restrict__ att_src, const float* __restrict__ att_dst,
    unsigned short* __restrict__ hb, float* __restrict__ a_s,
    float* __restrict__ a_d)
{
    __shared__ unsigned short Ws[INF_ * OUTF];   // 16 KB (bf16 W tile)
    __shared__ unsigned short Xs[64 * XSTRIDE];  // 17 KB (bf16 x tile)

    {   // zero gden/g_num (needs first 131 blocks; grid = 2000)
        int idx = blockIdx.x * 256 + threadIdx.x;
        if (idx < NG) gden[idx] = 0.f;
        else if (idx < NG + NG * OUTF) g_num[idx - NG] = 0.f;
    }

    const int r   = blockIdx.x & 7;
    const int oct = blockIdx.x >> 3;

    if (r < NPART) {
        // ---------------- adjacency part ----------------
        const int lo = r * PSIZE;                // part r's dst range
        const int e0 = oct * CHUNKE;
        const int e1 = (e0 + CHUNKE < NE) ? e0 + CHUNKE : NE;
        for (int e = e0 + threadIdx.x; e < e1; e += 256) {
            int d = ei[NE + e];
            unsigned int rel = (unsigned int)(d - lo);
            if (rel < PSIZE) {
                int s = ei[e];
                int p = atomicAdd(&deg[d], 1);
                if (p < CAP) adj[(size_t)d * CAP + p] = (unsigned short)s;
            }
        }
        return;
    }

    // ---------------- GEMM part ----------------
    const int bid = oct * 4 + (r - 4);           // 0..999, need <782
    if (bid >= GEMM_BLOCKS) return;
    const int n0 = bid * 64;

    // stage W as bf16: 8 float4 loads/thread -> ushort4 stores
    #pragma unroll
    for (int it = 0; it < 8; it++) {
        int i = it * 256 + threadIdx.x;          // float4 granule id
        float4 v = ((const float4*)W)[i];
        ushort4 b;
        b.x = f2bf(v.x); b.y = f2bf(v.y); b.z = f2bf(v.z); b.w = f2bf(v.w);
        ((ushort4*)Ws)[i] = b;
    }

    // stage x tile: 64 rows x 128 cols, coalesced float4 loads -> bf16 LDS
    #pragma unroll
    for (int it = 0; it < 8; it++) {
        int idx = it * 256 + threadIdx.x;      // float4 granule id
        int row = idx >> 5;                    // 32 float4 per row
        int c4  = idx & 31;
        int n = n0 + row;
        if (n > NN - 1) n = NN - 1;            // clamp tail (stores guarded)
        float4 v = ((const float4*)(x + (size_t)n * INF_))[c4];
        ushort4 b;
        b.x = f2bf(v.x); b.y = f2bf(v.y); b.z = f2bf(v.z); b.w = f2bf(v.w);
        *(ushort4*)&Xs[row * XSTRIDE + c4 * 4] = b;
    }
    __syncthreads();

    const int colg = threadIdx.x & 15;
    const int rowg = threadIdx.x >> 4;

    const unsigned short* xr[4];
    #pragma unroll
    for (int rr = 0; rr < 4; rr++)
        xr[rr] = &Xs[(rowg * 4 + rr) * XSTRIDE];

    float acc[4][4];
    #pragma unroll
    for (int rr = 0; rr < 4; rr++)
        #pragma unroll
        for (int c = 0; c < 4; c++) acc[rr][c] = 0.f;

    for (int k8 = 0; k8 < INF_ / 8; k8++) {
        uint4 xv[4];                           // 8 bf16 per row
        #pragma unroll
        for (int rr = 0; rr < 4; rr++)
            xv[rr] = *(const uint4*)(xr[rr] + k8 * 8);
        #pragma unroll
        for (int kk = 0; kk < 8; kk++) {
            uint2 wu = *(const uint2*)&Ws[(k8 * 8 + kk) * OUTF + colg * 4];
            float w0 = bf2f(wu.x & 0xffffu), w1 = bf2f(wu.x >> 16);
            float w2 = bf2f(wu.y & 0xffffu), w3 = bf2f(wu.y >> 16);
            #pragma unroll
            for (int rr = 0; rr < 4; rr++) {
                unsigned int pair = ((const unsigned int*)&xv[rr])[kk >> 1];
                float xs_ = bf2f((kk & 1) ? (pair >> 16) : (pair & 0xffffu));
                acc[rr][0] = fmaf(xs_, w0, acc[rr][0]);
                acc[rr][1] = fmaf(xs_, w1, acc[rr][1]);
                acc[rr][2] = fmaf(xs_, w2, acc[rr][2]);
                acc[rr][3] = fmaf(xs_, w3, acc[rr][3]);
            }
        }
    }

    float asv[4], adv[4];
    #pragma unroll
    for (int c = 0; c < 4; c++) {
        asv[c] = att_src[colg * 4 + c];
        adv[c] = att_dst[colg * 4 + c];
    }

    #pragma unroll
    for (int rr = 0; rr < 4; rr++) {
        const int n = n0 + rowg * 4 + rr;
        const bool valid = (n < NN);
        if (valid) {
            ushort4 o;
            o.x = f2bf(acc[rr][0]); o.y = f2bf(acc[rr][1]);
            o.z = f2bf(acc[rr][2]); o.w = f2bf(acc[rr][3]);
            ((ushort4*)(hb + (size_t)n * OUTF))[colg] = o;
        }
        float vs = acc[rr][0]*asv[0] + acc[rr][1]*asv[1] + acc[rr][2]*asv[2] + acc[rr][3]*asv[3];
        float vd = acc[rr][0]*adv[0] + acc[rr][1]*adv[1] + acc[rr][2]*adv[2] + acc[rr][3]*adv[3];
        vs += __shfl_xor(vs, 1, 64);           // lane pair (colg, colg^1) = one head
        vd += __shfl_xor(vd, 1, 64);
        if (valid && !(colg & 1)) {
            a_s[n * 8 + (colg >> 1)] = vs;
            a_d[n * 8 + (colg >> 1)] = vd;
        }
    }
}

// ---------------- GAT aggregation: wave = 8 edge-slots x 8 col-octets ------
__global__ __launch_bounds__(256) void k_aggr(
    const unsigned short* __restrict__ hb, const float* __restrict__ a_s,
    const float* __restrict__ a_d, const int* __restrict__ deg,
    const unsigned short* __restrict__ adj, const float* __restrict__ bias,
    const float* __restrict__ w_rel, const float* __restrict__ w_root,
    float* __restrict__ out, float* __restrict__ t_rel, float* __restrict__ t_root)
{
    const int wid  = threadIdx.x >> 6;
    const int lane = threadIdx.x & 63;
    const int g    = lane >> 3;     // edge slot 0..7
    const int c8   = lane & 7;      // head / col-octet 0..7
    const int n    = blockIdx.x * 4 + wid;
    if (n >= NN) return;

    const float ad_n = a_d[n * 8 + c8];

    float acc[8];
    #pragma unroll
    for (int k = 0; k < 8; k++) acc[k] = 0.f;
    float den = 0.f;

    // self-loop handled by edge slot 0
    if (g == 0) {
        float e0 = a_s[n * 8 + c8] + ad_n;
        e0 = e0 > 0.f ? e0 : 0.2f * e0;
        float ex0 = __expf(e0);
        uint4 hv = *(const uint4*)(hb + (size_t)n * OUTF + c8 * 8);
        acc[0] = ex0 * bf2f(hv.x & 0xffffu); acc[1] = ex0 * bf2f(hv.x >> 16);
        acc[2] = ex0 * bf2f(hv.y & 0xffffu); acc[3] = ex0 * bf2f(hv.y >> 16);
        acc[4] = ex0 * bf2f(hv.z & 0xffffu); acc[5] = ex0 * bf2f(hv.z >> 16);
        acc[6] = ex0 * bf2f(hv.w & 0xffffu); acc[7] = ex0 * bf2f(hv.w >> 16);
        den = ex0;
    }

    const int cnt = min(deg[n], CAP);
    const unsigned short* lst = adj + (size_t)n * CAP;
    for (int i = g; i < cnt; i += 8) {
        int s = lst[i];                                   // uniform per group
        float as = a_s[s * 8 + c8];
        uint4 hv = *(const uint4*)(hb + (size_t)s * OUTF + c8 * 8);
        float e = as + ad_n;
        e = e > 0.f ? e : 0.2f * e;
        float ex = __expf(e);
        acc[0] = fmaf(ex, bf2f(hv.x & 0xffffu), acc[0]);
        acc[1] = fmaf(ex, bf2f(hv.x >> 16),     acc[1]);
        acc[2] = fmaf(ex, bf2f(hv.y & 0xffffu), acc[2]);
        acc[3] = fmaf(ex, bf2f(hv.y >> 16),     acc[3]);
        acc[4] = fmaf(ex, bf2f(hv.z & 0xffffu), acc[4]);
        acc[5] = fmaf(ex, bf2f(hv.z >> 16),     acc[5]);
        acc[6] = fmaf(ex, bf2f(hv.w & 0xffffu), acc[6]);
        acc[7] = fmaf(ex, bf2f(hv.w >> 16),     acc[7]);
        den += ex;
    }

    // butterfly reduce across edge slots (g bits = lane bits 3..5)
    #pragma unroll
    for (int m = 8; m < 64; m <<= 1) {
        den += __shfl_xor(den, m, 64);
        #pragma unroll
        for (int k = 0; k < 8; k++) acc[k] += __shfl_xor(acc[k], m, 64);
    }

    const float inv = 1.f / (den + 1e-16f);
    float o[8];
    #pragma unroll
    for (int k = 0; k < 8; k++) o[k] = acc[k] * inv + bias[c8 * 8 + k];

    if (g == 0) {
        float4 o0 = make_float4(o[0], o[1], o[2], o[3]);
        float4 o1 = make_float4(o[4], o[5], o[6], o[7]);
        float4* op = (float4*)(out + (size_t)n * OUTF + c8 * 8);
        op[0] = o0; op[1] = o1;
    }

    // pooling-score projections: vr = sum_j o_j*w_rel_j (cols dup across g)
    float vr = 0.f, vt = 0.f;
    #pragma unroll
    for (int k = 0; k < 8; k++) {
        vr = fmaf(o[k], w_rel[c8 * 8 + k], vr);
        vt = fmaf(o[k], w_root[c8 * 8 + k], vt);
    }
    #pragma unroll
    for (int m = 1; m < 8; m <<= 1) {
        vr += __shfl_xor(vr, m, 64);
        vt += __shfl_xor(vt, m, 64);
    }
    if (lane == 0) { t_rel[n] = vr; t_root[n] = vt; }
}

// ---------------- fused pooling: score gather + softmax-numerator pool -----
__global__ __launch_bounds__(256) void k_score_pool(
    const int* __restrict__ deg, const unsigned short* __restrict__ adj,
    const float* __restrict__ t_rel, const float* __restrict__ t_root,
    const float* __restrict__ pool_b, const int* __restrict__ batch,
    const float* __restrict__ out,
    float* __restrict__ gden, float* __restrict__ g_num)
{
    __shared__ float ex_s[32];
    __shared__ int   b_s[32];

    const int wid  = threadIdx.x >> 6;
    const int lane = threadIdx.x & 63;
    const int sub  = lane >> 3;     // node within wave (0..7)
    const int g    = lane & 7;      // slot
    const int base_n = blockIdx.x * 32;
    const int n    = base_n + wid * 8 + sub;

    const int cnt = (n < NN) ? min(deg[n], CAP) : 0;
    const unsigned short* lst = adj + (size_t)n * CAP;
    float acc = 0.f;
    for (int i = g; i < cnt; i += 8) acc += t_rel[lst[i]];
    #pragma unroll
    for (int m = 1; m < 8; m <<= 1) acc += __shfl_xor(acc, m, 64);

    if (g == 0) {
        const int slot = wid * 8 + sub;
        if (n < NN) {
            float ex = __expf(acc + t_root[n] + pool_b[0]);
            ex_s[slot] = ex;
            b_s[slot]  = batch[n];
        } else {
            ex_s[slot] = 0.f;
            b_s[slot]  = -1;
        }
    }
    __syncthreads();

    if (threadIdx.x == 0) {           // gden run-length flush (batch sorted)
        float racc = 0.f;
        int bcur = -1;
        for (int i = 0; i < 32; i++) {
            int b = b_s[i];
            if (b != bcur) {
                if (bcur >= 0) atomicAdd(&gden[bcur], racc);
                bcur = b; racc = 0.f;
            }
            racc += ex_s[i];
        }
        if (bcur >= 0) atomicAdd(&gden[bcur], racc);
    }

    // phase 2: wave wid accumulates its 8 nodes; lane = feature j
    const int j = lane;
    float facc = 0.f;
    int bcur = -1;
    for (int i = 0; i < 8; i++) {
        const int slot = wid * 8 + i;
        const int n2 = base_n + slot;
        if (n2 >= NN) break;
        int b = b_s[slot];                         // wave-uniform
        if (b != bcur) {
            if (bcur >= 0) atomicAdd(&g_num[bcur * OUTF + j], facc);
            bcur = b; facc = 0.f;
        }
        facc = fmaf(out[(size_t)n2 * OUTF + j], ex_s[slot], facc);
    }
    if (bcur >= 0) atomicAdd(&g_num[bcur * OUTF + j], facc);
}

// ---------------- g[b,j] = g_num[b,j] / (gden[b] + eps) --------------------
__global__ __launch_bounds__(256) void k_gfinal(
    const float* __restrict__ g_num, const float* __restrict__ gden,
    float* __restrict__ g)
{
    int i = blockIdx.x * 256 + threadIdx.x;
    if (i < NG * OUTF) g[i] = g_num[i] / (gden[i >> 6] + 1e-16f);
}

extern "C" void kernel_launch(void* const* d_in, const int* in_sizes, int n_in,
                              void* d_out, int out_size, void* d_ws, size_t ws_size,
                              hipStream_t stream)
{
    const float* x        = (const float*)d_in[0];
    const int*   ei       = (const int*)  d_in[1];
    const int*   batch    = (const int*)  d_in[2];
    const float* W        = (const float*)d_in[3];
    const float* att_src  = (const float*)d_in[4];
    const float* att_dst  = (const float*)d_in[5];
    const float* bias     = (const float*)d_in[6];
    const float* w_rel    = (const float*)d_in[7];
    const float* pool_b   = (const float*)d_in[8];
    const float* w_root   = (const float*)d_in[9];

    float* out_nodes = (float*)d_out;                       // [NN,64]
    float* g_out     = (float*)d_out + (size_t)NN * OUTF;   // [NG,64]

    // workspace layout (bytes)
    char* base = (char*)d_ws;
    unsigned short* hb = (unsigned short*)(base);           //  6,400,000 B
    float* a_s       = (float*)(base +  6400000);           //  1,600,000 B
    float* a_d       = (float*)(base +  8000000);           //  1,600,000 B
    float* t_rel     = (float*)(base +  9600000);           //    200,000 B
    float* t_root    = (float*)(base +  9800000);           //    200,000 B
    float* gden      = (float*)(base + 10000000);           //      2,048 B
    float* g_num     = (float*)(base + 10002048);           //    131,072 B
    int*   deg       = (int*)  (base + 10133120);           //    200,000 B
    unsigned short* adjl = (unsigned short*)(base + 10333120); // 6,400,000 B
    // total: 16,733,120 B

    hipMemsetAsync(deg, 0, (size_t)NN * 4, stream);   // adj part needs zeroed deg

    k_front<<<FRONT_BLOCKS, 256, 0, stream>>>(
        ei, deg, adjl, gden, g_num,
        x, W, att_src, att_dst, hb, a_s, a_d);
    k_aggr<<<(NN + 3) / 4, 256, 0, stream>>>(hb, a_s, a_d, deg, adjl, bias,
                                             w_rel, w_root, out_nodes, t_rel, t_root);
    k_score_pool<<<(NN + 31) / 32, 256, 0, stream>>>(deg, adjl, t_rel, t_root,
                                                     pool_b, batch, out_nodes,
                                                     gden, g_num);
    k_gfinal<<<(NG * OUTF + 255) / 256, 256, 0, stream>>>(g_num, gden, g_out);
}